// Round 2
// baseline (186.840 us; speedup 1.0000x reference)
//
#include <hip/hip_runtime.h>

#define NTOK 49
#define NH 4
#define HD 32
#define CIN 384
#define NW 64
#define SCALE_F 0.1767766952966369f

__global__ __launch_bounds__(64) void win_attn_kernel(
    const float* __restrict__ qkv,
    const float* __restrict__ mask,
    const float* __restrict__ rot,
    float* __restrict__ out)
{
    const int h = blockIdx.x & 3;
    const int b = blockIdx.x >> 2;
    const int w = b & (NW - 1);
    const int lane = threadIdx.x;

    // q padded to 33 floats/row: lane-varying row reads hit distinct banks
    __shared__ float q_lds[NTOK][HD + 1];
    __shared__ float k_lds[NTOK][HD];
    __shared__ float v_lds[NTOK][HD];

    const float* base = qkv + (size_t)b * (NTOK * CIN) + h * HD;

    // Stage q (pre-scaled), k, v into LDS. 49*32 f32 each, float4 loads.
    for (int e = lane; e < (NTOK * HD / 4); e += 64) {
        const int n = e >> 3;
        const int d = (e & 7) << 2;
        const float* p = base + n * CIN + d;
        const float4 fq = *reinterpret_cast<const float4*>(p);
        const float4 fk = *reinterpret_cast<const float4*>(p + 128);
        const float4 fv = *reinterpret_cast<const float4*>(p + 256);
        q_lds[n][d + 0] = fq.x * SCALE_F;
        q_lds[n][d + 1] = fq.y * SCALE_F;
        q_lds[n][d + 2] = fq.z * SCALE_F;
        q_lds[n][d + 3] = fq.w * SCALE_F;
        k_lds[n][d + 0] = fk.x;
        k_lds[n][d + 1] = fk.y;
        k_lds[n][d + 2] = fk.z;
        k_lds[n][d + 3] = fk.w;
        v_lds[n][d + 0] = fv.x;
        v_lds[n][d + 1] = fv.y;
        v_lds[n][d + 2] = fv.z;
        v_lds[n][d + 3] = fv.w;
    }
    __syncthreads();

    if (lane < NTOK) {
        // q row for this lane into registers
        float qr[HD];
        #pragma unroll
        for (int d = 0; d < HD; ++d) qr[d] = q_lds[lane][d];

        const float* mrow = mask + (size_t)(h * NTOK + lane) * NTOK;
        const float* rrow = rot + (size_t)(w * NTOK + lane) * NTOK;

        // QK^T row + masks, fully in registers (all statically indexed)
        float a[NTOK];
        #pragma unroll
        for (int j = 0; j < NTOK; ++j) {
            float acc = 0.f;
            #pragma unroll
            for (int d = 0; d < HD; ++d) acc = fmaf(qr[d], k_lds[j][d], acc);
            a[j] = acc + mrow[j] + rrow[j];
        }

        // softmax (in registers)
        float m = a[0];
        #pragma unroll
        for (int j = 1; j < NTOK; ++j) m = fmaxf(m, a[j]);
        float s = 0.f;
        #pragma unroll
        for (int j = 0; j < NTOK; ++j) {
            a[j] = __expf(a[j] - m);
            s += a[j];
        }
        const float inv = 1.f / s;

        // PV: o[d] = sum_j a[j] * v[j][d]  (v reads are wave-uniform -> broadcast)
        float o[HD];
        #pragma unroll
        for (int d = 0; d < HD; ++d) o[d] = 0.f;
        #pragma unroll
        for (int j = 0; j < NTOK; ++j) {
            const float p = a[j];
            #pragma unroll
            for (int d = 0; d < HD; ++d) o[d] = fmaf(p, v_lds[j][d], o[d]);
        }

        // out[b, n=lane, h*32 + d], float4 stores
        float* orow = out + (size_t)b * (NTOK * NH * HD) + lane * (NH * HD) + h * HD;
        #pragma unroll
        for (int d = 0; d < HD; d += 4) {
            float4 u;
            u.x = o[d + 0] * inv;
            u.y = o[d + 1] * inv;
            u.z = o[d + 2] * inv;
            u.w = o[d + 3] * inv;
            *reinterpret_cast<float4*>(orow + d) = u;
        }
    }
}

extern "C" void kernel_launch(void* const* d_in, const int* in_sizes, int n_in,
                              void* d_out, int out_size, void* d_ws, size_t ws_size,
                              hipStream_t stream) {
    const float* qkv  = (const float*)d_in[0];
    const float* mask = (const float*)d_in[1];
    const float* rot  = (const float*)d_in[2];
    float* out = (float*)d_out;

    const int Btot = in_sizes[0] / (NTOK * CIN);  // 4096
    dim3 grid(Btot * NH);
    win_attn_kernel<<<grid, 64, 0, stream>>>(qkv, mask, rot, out);
}

// Round 3
// 166.199 us; speedup vs baseline: 1.1242x; 1.1242x over previous
//
#include <hip/hip_runtime.h>

#define NTOK 49
#define NH 4
#define HD 32
#define CIN 384
#define NW 64
#define SCALE_F 0.1767766952966369f

__global__ __launch_bounds__(64) void win_attn_kernel(
    const float* __restrict__ qkv,
    const float* __restrict__ mask,
    const float* __restrict__ rot,
    float* __restrict__ out)
{
    const int h = blockIdx.x & 3;
    const int b = blockIdx.x >> 2;
    const int w = b & (NW - 1);
    const int lane = threadIdx.x;

    __shared__ float k_lds[NTOK][HD];
    __shared__ float v_lds[NTOK][HD];

    const float* base = qkv + (size_t)b * (NTOK * CIN) + h * HD;

    // Stage k, v into LDS (q goes straight to registers below).
    for (int e = lane; e < (NTOK * HD / 4); e += 64) {
        const int n = e >> 3;
        const int d = (e & 7) << 2;
        const float* p = base + n * CIN + d;
        const float4 fk = *reinterpret_cast<const float4*>(p + 128);
        const float4 fv = *reinterpret_cast<const float4*>(p + 256);
        k_lds[n][d + 0] = fk.x;
        k_lds[n][d + 1] = fk.y;
        k_lds[n][d + 2] = fk.z;
        k_lds[n][d + 3] = fk.w;
        v_lds[n][d + 0] = fv.x;
        v_lds[n][d + 1] = fv.y;
        v_lds[n][d + 2] = fv.z;
        v_lds[n][d + 3] = fv.w;
    }
    __syncthreads();

    if (lane < NTOK) {
        // q row for this lane straight from global into registers (pre-scaled)
        float qr[HD];
        const float* qp = base + lane * CIN;
        #pragma unroll
        for (int d = 0; d < HD; d += 4) {
            const float4 fq = *reinterpret_cast<const float4*>(qp + d);
            qr[d + 0] = fq.x * SCALE_F;
            qr[d + 1] = fq.y * SCALE_F;
            qr[d + 2] = fq.z * SCALE_F;
            qr[d + 3] = fq.w * SCALE_F;
        }

        const float* mrow = mask + (size_t)(h * NTOK + lane) * NTOK;
        const float* rrow = rot + (size_t)(w * NTOK + lane) * NTOK;

        // QK^T row + masks, fully in registers (all statically indexed)
        float a[NTOK];
        #pragma unroll
        for (int j = 0; j < NTOK; ++j) {
            float acc = 0.f;
            #pragma unroll
            for (int d = 0; d < HD; ++d) acc = fmaf(qr[d], k_lds[j][d], acc);
            a[j] = acc + mrow[j] + rrow[j];
        }

        // softmax (in registers)
        float m = a[0];
        #pragma unroll
        for (int j = 1; j < NTOK; ++j) m = fmaxf(m, a[j]);
        float s = 0.f;
        #pragma unroll
        for (int j = 0; j < NTOK; ++j) {
            a[j] = __expf(a[j] - m);
            s += a[j];
        }
        const float inv = 1.f / s;

        // PV: o[d] = sum_j a[j] * v[j][d]  (v reads are wave-uniform -> broadcast)
        float o[HD];
        #pragma unroll
        for (int d = 0; d < HD; ++d) o[d] = 0.f;
        #pragma unroll
        for (int j = 0; j < NTOK; ++j) {
            const float p = a[j];
            #pragma unroll
            for (int d = 0; d < HD; ++d) o[d] = fmaf(p, v_lds[j][d], o[d]);
        }

        // out[b, n=lane, h*32 + d], float4 stores
        float* orow = out + (size_t)b * (NTOK * NH * HD) + lane * (NH * HD) + h * HD;
        #pragma unroll
        for (int d = 0; d < HD; d += 4) {
            float4 u;
            u.x = o[d + 0] * inv;
            u.y = o[d + 1] * inv;
            u.z = o[d + 2] * inv;
            u.w = o[d + 3] * inv;
            *reinterpret_cast<float4*>(orow + d) = u;
        }
    }
}

extern "C" void kernel_launch(void* const* d_in, const int* in_sizes, int n_in,
                              void* d_out, int out_size, void* d_ws, size_t ws_size,
                              hipStream_t stream) {
    const float* qkv  = (const float*)d_in[0];
    const float* mask = (const float*)d_in[1];
    const float* rot  = (const float*)d_in[2];
    float* out = (float*)d_out;

    const int Btot = in_sizes[0] / (NTOK * CIN);  // 4096
    dim3 grid(Btot * NH);
    win_attn_kernel<<<grid, 64, 0, stream>>>(qkv, mask, rot, out);
}

// Round 5
// 112.180 us; speedup vs baseline: 1.6655x; 1.4815x over previous
//
#include <hip/hip_runtime.h>

#define NTOK 49
#define NH 4
#define HD 32
#define CIN 384
#define NW 64
#define NPAD 64
#define SCALE_F 0.1767766952966369f

typedef _Float16 f16x8 __attribute__((ext_vector_type(8)));
typedef float f32x16 __attribute__((ext_vector_type(16)));
typedef __fp16 fp16x2 __attribute__((ext_vector_type(2)));

__device__ __forceinline__ unsigned int pkh(float a, float b) {
    fp16x2 h = __builtin_amdgcn_cvt_pkrtz(a, b);
    return __builtin_bit_cast(unsigned int, h);
}

// cmaskT[w*4+h][j][i] = mask[h][i][j] + rot[w][i][j], padded to 64x64,
// j>=49 -> -1e30 (kills padded keys in softmax), i>=49 -> 0.
__global__ __launch_bounds__(64) void prep_cmask(
    const float* __restrict__ mask,
    const float* __restrict__ rot,
    float* __restrict__ cmT)
{
    const int wh = blockIdx.x;          // w*4 + h
    const int w = wh >> 2, h = wh & 3;
    const int i = threadIdx.x;          // 0..63
    for (int j = 0; j < NPAD; ++j) {
        float v;
        if (j >= NTOK) v = -1e30f;
        else if (i >= NTOK) v = 0.f;
        else v = mask[(h * NTOK + i) * NTOK + j] + rot[(w * NTOK + i) * NTOK + j];
        cmT[((size_t)wh * NPAD + j) * NPAD + i] = v;
    }
}

// One wave per (b,h). S^T = K*Q^T via mfma_32x32x16_f16 (C-layout: col=i=lane&31,
// row=j=(reg&3)+8*(reg>>2)+4*(lane>>5)+32*tile). Softmax lane-local + shfl_xor(32).
// O = P*V with P-fragments built in-register (cvt_pkrtz + one lane^32 exchange).
template<bool USE_CM>
__global__ __launch_bounds__(64) void win_attn_mfma(
    const float* __restrict__ qkv,
    const float* __restrict__ mask,
    const float* __restrict__ rot,
    const float* __restrict__ cmT,
    float* __restrict__ out)
{
    const int h = blockIdx.x & 3;
    const int b = blockIdx.x >> 2;
    const int w = b & (NW - 1);
    const int lane = threadIdx.x;
    const int l31 = lane & 31;
    const int hl = lane >> 5;

    __shared__ _Float16 Qs[NPAD * HD];   // rows >= 49 zeroed
    __shared__ _Float16 Ks[NPAD * HD];

    const float* base = qkv + (size_t)b * (NTOK * CIN) + h * HD;

    // ---- stage Q (pre-scaled) and K as f16 into LDS ----
    #pragma unroll
    for (int t8 = 0; t8 < 8; ++t8) {
        const int idx = lane + t8 * 64;    // 0..511
        const int n = idx >> 3;            // row 0..63
        const int c = idx & 7;             // float4 chunk
        float4 fq = make_float4(0.f, 0.f, 0.f, 0.f);
        float4 fk = fq;
        if (n < NTOK) {
            const float* p = base + n * CIN + c * 4;
            fq = *reinterpret_cast<const float4*>(p);
            fk = *reinterpret_cast<const float4*>(p + 128);
        }
        uint2 uq, uk;
        uq.x = pkh(fq.x * SCALE_F, fq.y * SCALE_F);
        uq.y = pkh(fq.z * SCALE_F, fq.w * SCALE_F);
        uk.x = pkh(fk.x, fk.y);
        uk.y = pkh(fk.z, fk.w);
        *reinterpret_cast<uint2*>(&Qs[n * HD + c * 4]) = uq;
        *reinterpret_cast<uint2*>(&Ks[n * HD + c * 4]) = uk;
    }

    // ---- combined mask values (issue loads early; independent of LDS) ----
    float cm[2][2][16];
    #pragma unroll
    for (int it = 0; it < 2; ++it) {
        #pragma unroll
        for (int jt = 0; jt < 2; ++jt) {
            #pragma unroll
            for (int r = 0; r < 16; ++r) {
                const int j = (r & 3) + 8 * (r >> 2) + 4 * hl + 32 * jt;
                const int i = l31 + 32 * it;
                if (USE_CM) {
                    cm[it][jt][r] = cmT[((size_t)(w * 4 + h) * NPAD + j) * NPAD + i];
                } else {
                    float v;
                    if (j >= NTOK) v = -1e30f;
                    else if (i >= NTOK) v = 0.f;
                    else v = mask[(h * NTOK + i) * NTOK + j] + rot[(w * NTOK + i) * NTOK + j];
                    cm[it][jt][r] = v;
                }
            }
        }
    }

    __syncthreads();

    // ---- A/B fragments from LDS: lane holds row (l31+32*tile), d-slice ks*16+hl*8 ----
    f16x8 ka[2][2], qa[2][2];   // [tile][ks]
    #pragma unroll
    for (int t = 0; t < 2; ++t) {
        #pragma unroll
        for (int ks = 0; ks < 2; ++ks) {
            ka[t][ks] = *reinterpret_cast<const f16x8*>(&Ks[(l31 + 32 * t) * HD + ks * 16 + hl * 8]);
            qa[t][ks] = *reinterpret_cast<const f16x8*>(&Qs[(l31 + 32 * t) * HD + ks * 16 + hl * 8]);
        }
    }

    // ---- S^T = K * Q^T ----
    f32x16 acc[2][2];           // [it][jt]
    #pragma unroll
    for (int it = 0; it < 2; ++it) {
        #pragma unroll
        for (int jt = 0; jt < 2; ++jt) {
            f32x16 a;
            #pragma unroll
            for (int r = 0; r < 16; ++r) a[r] = 0.f;
            a = __builtin_amdgcn_mfma_f32_32x32x16_f16(ka[jt][0], qa[it][0], a, 0, 0, 0);
            a = __builtin_amdgcn_mfma_f32_32x32x16_f16(ka[jt][1], qa[it][1], a, 0, 0, 0);
            acc[it][jt] = a;
        }
    }

    // ---- + masks, softmax over j (32 lane-local values + lane^32 partner), scale by 1/sum ----
    #pragma unroll
    for (int it = 0; it < 2; ++it) {
        float m = -3e38f;
        #pragma unroll
        for (int jt = 0; jt < 2; ++jt) {
            #pragma unroll
            for (int r = 0; r < 16; ++r) {
                acc[it][jt][r] += cm[it][jt][r];
                m = fmaxf(m, acc[it][jt][r]);
            }
        }
        m = fmaxf(m, __shfl_xor(m, 32));
        float s = 0.f;
        #pragma unroll
        for (int jt = 0; jt < 2; ++jt) {
            #pragma unroll
            for (int r = 0; r < 16; ++r) {
                const float e = __expf(acc[it][jt][r] - m);
                acc[it][jt][r] = e;
                s += e;
            }
        }
        s += __shfl_xor(s, 32);
        const float inv = 1.f / s;
        #pragma unroll
        for (int jt = 0; jt < 2; ++jt) {
            #pragma unroll
            for (int r = 0; r < 16; ++r)
                acc[it][jt][r] *= inv;
        }
    }

    // ---- O = P * V ----
    f32x16 oacc[2];
    #pragma unroll
    for (int it = 0; it < 2; ++it) {
        #pragma unroll
        for (int r = 0; r < 16; ++r) oacc[it][r] = 0.f;
    }

    #pragma unroll
    for (int ks = 0; ks < 4; ++ks) {
        // V B-fragment direct from global: lane holds V[16ks+8hl+e][d=l31]
        unsigned int vd[4];
        #pragma unroll
        for (int ep = 0; ep < 4; ++ep) {
            const int j0 = 16 * ks + 8 * hl + 2 * ep;
            float v0 = 0.f, v1 = 0.f;
            if (j0 < NTOK)
                v0 = qkv[((size_t)b * NTOK + j0) * CIN + 256 + h * HD + l31];
            if (j0 + 1 < NTOK)
                v1 = qkv[((size_t)b * NTOK + j0 + 1) * CIN + 256 + h * HD + l31];
            vd[ep] = pkh(v0, v1);
        }
        uint4 vu = make_uint4(vd[0], vd[1], vd[2], vd[3]);
        const f16x8 vb = __builtin_bit_cast(f16x8, vu);

        const int jt = ks >> 1;
        const int r8 = 8 * (ks & 1);
        #pragma unroll
        for (int it = 0; it < 2; ++it) {
            // pack own j-pairs; exchange the half the partner needs (lane ^ 32)
            const unsigned int lo0 = pkh(acc[it][jt][r8 + 0], acc[it][jt][r8 + 1]);
            const unsigned int lo1 = pkh(acc[it][jt][r8 + 2], acc[it][jt][r8 + 3]);
            const unsigned int hi0 = pkh(acc[it][jt][r8 + 4], acc[it][jt][r8 + 5]);
            const unsigned int hi1 = pkh(acc[it][jt][r8 + 6], acc[it][jt][r8 + 7]);
            const unsigned int x0 = hl ? lo0 : hi0;
            const unsigned int x1 = hl ? lo1 : hi1;
            const unsigned int y0 = (unsigned int)__shfl_xor((int)x0, 32);
            const unsigned int y1 = (unsigned int)__shfl_xor((int)x1, 32);
            uint4 pu;
            pu.x = hl ? y0 : lo0;
            pu.y = hl ? y1 : lo1;
            pu.z = hl ? hi0 : y0;
            pu.w = hl ? hi1 : y1;
            const f16x8 pa = __builtin_bit_cast(f16x8, pu);
            oacc[it] = __builtin_amdgcn_mfma_f32_32x32x16_f16(pa, vb, oacc[it], 0, 0, 0);
        }
    }

    // ---- store: O[i][d], d = l31, i from C-layout rows ----
    #pragma unroll
    for (int it = 0; it < 2; ++it) {
        #pragma unroll
        for (int r = 0; r < 16; ++r) {
            const int i = (r & 3) + 8 * (r >> 2) + 4 * hl + 32 * it;
            if (i < NTOK)
                out[((size_t)b * NTOK + i) * (NH * HD) + h * HD + l31] = oacc[it][r];
        }
    }
}

extern "C" void kernel_launch(void* const* d_in, const int* in_sizes, int n_in,
                              void* d_out, int out_size, void* d_ws, size_t ws_size,
                              hipStream_t stream) {
    const float* qkv  = (const float*)d_in[0];
    const float* mask = (const float*)d_in[1];
    const float* rot  = (const float*)d_in[2];
    float* out = (float*)d_out;

    const int Btot = in_sizes[0] / (NTOK * CIN);  // 4096
    dim3 grid(Btot * NH);

    const size_t cm_bytes = (size_t)NW * NH * NPAD * NPAD * sizeof(float);  // 4 MiB
    if (ws_size >= cm_bytes && d_ws != nullptr) {
        float* cmT = (float*)d_ws;
        prep_cmask<<<dim3(NW * NH), 64, 0, stream>>>(mask, rot, cmT);
        win_attn_mfma<true><<<grid, 64, 0, stream>>>(qkv, mask, rot, cmT, out);
    } else {
        win_attn_mfma<false><<<grid, 64, 0, stream>>>(qkv, mask, rot, nullptr, out);
    }
}